// Round 4
// baseline (520.306 us; speedup 1.0000x reference)
//
#include <hip/hip_runtime.h>

typedef unsigned long long u64;

#define CH 256   // cols (boxes) per scan chunk
#define CW 4     // 64-bit words per chunk

// ---------------- K1a: partial rank counts ----------------
__global__ void k_rank_part(const float* __restrict__ preds, int n, int cpb,
                            int* __restrict__ pos) {
  __shared__ float cs[1024];
  int c0 = blockIdx.y * cpb;
  int cn = min(cpb, n - c0);
  for (int j = threadIdx.x; j < cn; j += blockDim.x)
    cs[j] = preds[(c0 + j) * 5 + 4];
  __syncthreads();
  int i = blockIdx.x * blockDim.x + threadIdx.x;
  if (i >= n) return;
  float ci = preds[i * 5 + 4];
  int cnt = 0;
  for (int j = 0; j < cn; ++j) {
    float cj = cs[j];
    int jj = c0 + j;
    cnt += (cj > ci) || (cj == ci && jj < i);
  }
  atomicAdd(&pos[i], cnt);
}

// ---------------- K1b: scatter into sorted order ----------------
__global__ void k_rank_scatter(const float* __restrict__ preds,
                               const int* __restrict__ pos, int n,
                               float* __restrict__ sboxes, int* __restrict__ sidx) {
  int i = blockIdx.x * blockDim.x + threadIdx.x;
  if (i >= n) return;
  int p = pos[i];
  sboxes[p * 4 + 0] = preds[i * 5 + 0];
  sboxes[p * 4 + 1] = preds[i * 5 + 1];
  sboxes[p * 4 + 2] = preds[i * 5 + 2];
  sboxes[p * 4 + 3] = preds[i * 5 + 3];
  sidx[p] = i;
}

// ---------------- K2: suppression bitmask, row-major ----------------
// M[row*nw + w] : bit j = IoU(row, col=w*64+j) > thresh && col > row
// Only w >= row/64 is written; sub-diagonal words are garbage but provably
// never influence the scan (they only AND into already-consumed words).
__global__ void k_mask(const float* __restrict__ sboxes, int n,
                       const float* __restrict__ thr_p,
                       u64* __restrict__ M, int nw) {
  int wx = blockIdx.x;  // column word
  int ry = blockIdx.y;  // row group
  if (wx < ry) return;
  int lane = threadIdx.x;

  __shared__ float4 cb[64];
  __shared__ float cbar[64];
  const float4* sb4 = (const float4*)sboxes;
  int col0 = wx * 64;
  int cj = col0 + lane;
  int cjc = cj < n ? cj : n - 1;
  {
    float4 b4 = sb4[cjc];
    cb[lane] = b4;
    cbar[lane] = __fmul_rn(__fsub_rn(b4.z, b4.x), __fsub_rn(b4.w, b4.y));
  }
  __syncthreads();

  int row = ry * 64 + lane;
  if (row >= n) return;
  float th = *thr_p;
  float4 r4 = sb4[row];
  float rarea = __fmul_rn(__fsub_rn(r4.z, r4.x), __fsub_rn(r4.w, r4.y));

  u64 w = 0;
#pragma unroll 8
  for (int j = 0; j < 64; ++j) {
    float4 c4 = cb[j];
    float ix1 = fmaxf(r4.x, c4.x);
    float iy1 = fmaxf(r4.y, c4.y);
    float ix2 = fminf(r4.z, c4.z);
    float iy2 = fminf(r4.w, c4.w);
    float iw = fmaxf(__fsub_rn(ix2, ix1), 0.0f);
    float ih = fmaxf(__fsub_rn(iy2, iy1), 0.0f);
    float inter = __fmul_rn(iw, ih);
    float denom = __fadd_rn(__fsub_rn(__fadd_rn(rarea, cbar[j]), inter), 1e-12f);
    float iou = __fdiv_rn(inter, denom);
    int col = col0 + j;
    bool sup = (col > row) && (col < n) && (iou > th);
    w |= ((u64)sup) << j;
  }
  M[(size_t)row * nw + wx] = w;
}

// ---------------- K3: incremental chunked greedy scan (1 WG, 4 waves) ----------------
// live[w]: running keep-mask. Per chunk: wave 0 scans 256 boxes using the LDS
// diag tile (double-buffered; prefetched by waves 2-3 during the previous scan);
// then all kept rows of the chunk are ANDed out of live[] with coalesced,
// register-batched (pipelined) row loads. No pointer-chase, no history re-scan.
__global__ void k_scan(const u64* __restrict__ M, int n, int nw, int maxp,
                       int* __restrict__ sel, int* __restrict__ cnt) {
  __shared__ u64 live[128];
  __shared__ u64 dbuf[2][CH][CW];
  __shared__ int plist[2][CH];
  __shared__ int pcnt[2];
  __shared__ int done_s;
  int t = threadIdx.x;           // 0..255
  int wave = t >> 6, lane = t & 63;
  int nch = (nw + CW - 1) / CW;

  if (t < 128) {
    u64 v = ~0ULL;
    int base = t * 64;
    if (t >= nw || base >= n) v = 0ULL;
    else if (base + 64 > n) v = (1ULL << (n - base)) - 1ULL;
    live[t] = v;
  }
  if (t == 0) { pcnt[0] = 0; pcnt[1] = 0; done_s = 0; }
  // prologue: load diag tile of chunk 0
  {
    int r = t;
    const u64* src = M + (size_t)r * nw;
#pragma unroll
    for (int q = 0; q < CW; ++q)
      dbuf[0][t][q] = (r < n && q < nw) ? src[q] : 0ULL;
  }
  __syncthreads();

  int out = 0;

  for (int c = 0; c < nch; ++c) {
    int cbuf = c & 1;

    // ---- phase A: apply previous chunk's kept rows to live[] ----
    if (c > 0 && t < 128 && t < nw) {
      int pb = (c - 1) & 1;
      int pcn = pcnt[pb];
      u64 acc = 0;
      for (int i0 = 0; i0 < pcn; i0 += 16) {
        int m = pcn - i0; if (m > 16) m = 16;
        int pl[16];
#pragma unroll
        for (int i = 0; i < 16; ++i)
          pl[i] = plist[pb][i0 + (i < m ? i : 0)];
#pragma unroll
        for (int i = 0; i < 16; ++i)
          if (i < m) acc |= M[(size_t)pl[i] * nw + t];
      }
      live[t] &= ~acc;
    }
    __syncthreads();

    // ---- phase B: wave 0 scans chunk c; waves 2-3 prefetch diag(c+1) ----
    if (wave == 0) {
      u64 rem[CW];
#pragma unroll
      for (int q = 0; q < CW; ++q) {
        int w = c * CW + q;
        rem[q] = (w < nw) ? live[w] : 0ULL;
      }
      int kc = 0;
      bool stop = false;
#pragma unroll
      for (int q = 0; q < CW; ++q) {
        if (stop) break;
        while (rem[q]) {
          int b = __builtin_ctzll(rem[q]);
          int pl_ = q * 64 + b;
          int p = c * CH + pl_;
          if (lane == 0) {
            plist[cbuf][kc] = p;
            if (out < maxp) sel[out] = p;
          }
          ++kc; ++out;
          if (out >= maxp) { stop = true; break; }
          u64 s0 = dbuf[cbuf][pl_][0];
          u64 s1 = dbuf[cbuf][pl_][1];
          u64 s2 = dbuf[cbuf][pl_][2];
          u64 s3 = dbuf[cbuf][pl_][3];
          rem[0] &= ~s0; rem[1] &= ~s1; rem[2] &= ~s2; rem[3] &= ~s3;
          u64 mle = (b == 63) ? ~0ULL : ((1ULL << (b + 1)) - 1ULL);
          rem[q] &= ~mle;
        }
      }
      if (lane == 0) {
        pcnt[cbuf] = kc;
        if (stop) done_s = 1;
      }
    } else if (wave >= 2) {
      int c1 = c + 1;
      if (c1 < nch) {
        int j = t - 128;  // 0..127 -> rows j, j+128
#pragma unroll
        for (int rr = 0; rr < 2; ++rr) {
          int rl = j + rr * 128;
          int r = c1 * CH + rl;
#pragma unroll
          for (int q = 0; q < CW; ++q) {
            int w = c1 * CW + q;
            dbuf[c1 & 1][rl][q] =
                (r < n && w < nw) ? M[(size_t)r * nw + w] : 0ULL;
          }
        }
      }
    }
    __syncthreads();
    if (done_s) break;
  }
  if (t == 0) *cnt = (out < maxp) ? out : maxp;
}

// ---------------- K4: gather outputs ----------------
__global__ void k_emit(const float* __restrict__ preds,
                       const int* __restrict__ sidx,
                       const int* __restrict__ sel,
                       const int* __restrict__ cnt,
                       int maxp, float* __restrict__ out) {
  int k = blockIdx.x * blockDim.x + threadIdx.x;
  if (k >= maxp) return;
  int nk = *cnt;
  if (k < nk) {
    int p = sel[k];
    int orig = sidx[p];
#pragma unroll
    for (int q = 0; q < 5; ++q) out[k * 5 + q] = preds[orig * 5 + q];
    out[(size_t)maxp * 5 + k] = (float)orig;
  } else {
#pragma unroll
    for (int q = 0; q < 5; ++q) out[k * 5 + q] = 0.0f;
    out[(size_t)maxp * 5 + k] = -1.0f;
  }
}

extern "C" void kernel_launch(void* const* d_in, const int* in_sizes, int n_in,
                              void* d_out, int out_size, void* d_ws, size_t ws_size,
                              hipStream_t stream) {
  const float* preds = (const float*)d_in[0];
  const float* thr   = (const float*)d_in[1];
  float* out = (float*)d_out;
  int n    = in_sizes[0] / 5;          // 8192
  int maxp = out_size / 6;             // 1000
  int nw   = (n + 63) / 64;            // 128

  char* ws = (char*)d_ws;
  u64* M = (u64*)ws;
  size_t off = (size_t)n * nw * sizeof(u64);                 // 8 MB
  float* sboxes = (float*)(ws + off);  off += (size_t)n * 4 * sizeof(float);
  int*   sidx   = (int*)(ws + off);    off += (size_t)n * sizeof(int);
  int*   sel    = (int*)(ws + off);    off += (size_t)maxp * sizeof(int);
  int*   cnt    = (int*)(ws + off);    off += sizeof(int) * 4;
  int*   pos    = (int*)(ws + off);

  hipMemsetAsync(pos, 0, (size_t)n * sizeof(int), stream);

  int cpb = 1024;
  hipLaunchKernelGGL(k_rank_part, dim3((n + 255) / 256, (n + cpb - 1) / cpb),
                     dim3(256), 0, stream, preds, n, cpb, pos);
  hipLaunchKernelGGL(k_rank_scatter, dim3((n + 255) / 256), dim3(256), 0, stream,
                     preds, pos, n, sboxes, sidx);
  hipLaunchKernelGGL(k_mask, dim3(nw, nw), dim3(64), 0, stream,
                     sboxes, n, thr, M, nw);
  hipLaunchKernelGGL(k_scan, dim3(1), dim3(256), 0, stream,
                     M, n, nw, maxp, sel, cnt);
  hipLaunchKernelGGL(k_emit, dim3((maxp + 255) / 256), dim3(256), 0, stream,
                     preds, sidx, sel, cnt, maxp, out);
}

// Round 5
// 471.884 us; speedup vs baseline: 1.1026x; 1.1026x over previous
//
#include <hip/hip_runtime.h>

typedef unsigned long long u64;

#define CH 256   // cols (boxes) per scan chunk
#define CW 4     // 64-bit words per chunk

// ---------------- K1: fused stable rank + scatter ----------------
// All n confidences staged in LDS (32KB for n=8192); each thread computes its
// box's stable descending rank and scatters box+index into sorted order.
__global__ __launch_bounds__(256) void k_rank(const float* __restrict__ preds,
                                              int n,
                                              float* __restrict__ sboxes,
                                              int* __restrict__ sidx) {
  __shared__ float cs[8192];
  for (int j = threadIdx.x; j < n; j += 256)
    cs[j] = preds[j * 5 + 4];
  __syncthreads();
  int i = blockIdx.x * 256 + threadIdx.x;
  if (i >= n) return;
  float ci = cs[i];
  int pos = 0;
  const float4* cs4 = (const float4*)cs;
  int n4 = n >> 2;
  for (int j4 = 0; j4 < n4; ++j4) {
    float4 c4 = cs4[j4];
    int jb = j4 * 4;
    pos += (c4.x > ci) || (c4.x == ci && (jb + 0) < i);
    pos += (c4.y > ci) || (c4.y == ci && (jb + 1) < i);
    pos += (c4.z > ci) || (c4.z == ci && (jb + 2) < i);
    pos += (c4.w > ci) || (c4.w == ci && (jb + 3) < i);
  }
  for (int j = n4 * 4; j < n; ++j)
    pos += (cs[j] > ci) || (cs[j] == ci && j < i);
  sboxes[pos * 4 + 0] = preds[i * 5 + 0];
  sboxes[pos * 4 + 1] = preds[i * 5 + 1];
  sboxes[pos * 4 + 2] = preds[i * 5 + 2];
  sboxes[pos * 4 + 3] = preds[i * 5 + 3];
  sidx[pos] = i;
}

// ---------------- K2: suppression bitmask, row-major ----------------
// M[row*nw + w] : bit j = IoU(row, col=w*64+j) > thresh && col > row
// Only w >= row/64 is written; sub-diagonal words are never consulted.
__global__ void k_mask(const float* __restrict__ sboxes, int n,
                       const float* __restrict__ thr_p,
                       u64* __restrict__ M, int nw) {
  int wx = blockIdx.x;  // column word
  int ry = blockIdx.y;  // row group
  if (wx < ry) return;
  int lane = threadIdx.x;

  __shared__ float4 cb[64];
  __shared__ float cbar[64];
  const float4* sb4 = (const float4*)sboxes;
  int col0 = wx * 64;
  int cj = col0 + lane;
  int cjc = cj < n ? cj : n - 1;
  {
    float4 b4 = sb4[cjc];
    cb[lane] = b4;
    cbar[lane] = __fmul_rn(__fsub_rn(b4.z, b4.x), __fsub_rn(b4.w, b4.y));
  }
  __syncthreads();

  int row = ry * 64 + lane;
  if (row >= n) return;
  float th = *thr_p;
  float4 r4 = sb4[row];
  float rarea = __fmul_rn(__fsub_rn(r4.z, r4.x), __fsub_rn(r4.w, r4.y));

  u64 w = 0;
#pragma unroll 8
  for (int j = 0; j < 64; ++j) {
    float4 c4 = cb[j];
    float ix1 = fmaxf(r4.x, c4.x);
    float iy1 = fmaxf(r4.y, c4.y);
    float ix2 = fminf(r4.z, c4.z);
    float iy2 = fminf(r4.w, c4.w);
    float iw = fmaxf(__fsub_rn(ix2, ix1), 0.0f);
    float ih = fmaxf(__fsub_rn(iy2, iy1), 0.0f);
    float inter = __fmul_rn(iw, ih);
    float denom = __fadd_rn(__fsub_rn(__fadd_rn(rarea, cbar[j]), inter), 1e-12f);
    float iou = __fdiv_rn(inter, denom);
    int col = col0 + j;
    bool sup = (col > row) && (col < n) && (iou > th);
    w |= ((u64)sup) << j;
  }
  M[(size_t)row * nw + wx] = w;
}

// ---------------- K3: incremental chunked greedy scan (1 WG, 4 waves) ----------------
// live[w]: running keep-mask. Per chunk:
//   A) all 256 threads apply prev chunk's kept rows to live[] — 2 threads/word,
//      8 UNCONDITIONAL clamped-index loads per batch (full MLP), LDS atomicAnd.
//   B) wave 0 scans chunk c from the LDS diag tile (double-buffered);
//      waves 2-3 prefetch chunk c+1's diag tile.
__global__ __launch_bounds__(256, 1)
void k_scan(const u64* __restrict__ M, int n, int nw, int maxp,
            int* __restrict__ sel, int* __restrict__ cnt) {
  __shared__ u64 live[128];
  __shared__ u64 dbuf[2][CH][CW];
  __shared__ int plist[2][CH];
  __shared__ int pcnt[2];
  __shared__ int done_s;
  int t = threadIdx.x;           // 0..255
  int wave = t >> 6;
  int nch = (nw + CW - 1) / CW;

  if (t < 128) {
    u64 v = ~0ULL;
    int base = t * 64;
    if (t >= nw || base >= n) v = 0ULL;
    else if (base + 64 > n) v = (1ULL << (n - base)) - 1ULL;
    live[t] = v;
  }
  if (t == 0) { pcnt[0] = 0; pcnt[1] = 0; done_s = 0; }
  // prologue: load diag tile of chunk 0 (rows 0..255 x words 0..3)
  {
    const u64* src = M + (size_t)t * nw;
#pragma unroll
    for (int q = 0; q < CW; ++q)
      dbuf[0][t][q] = (t < n && q < nw) ? src[q] : 0ULL;
  }
  __syncthreads();

  int out = 0;

  for (int c = 0; c < nch; ++c) {
    int cbuf = c & 1;

    // ---- phase A: apply previous chunk's kept rows to live[] ----
    {
      int pb = (c - 1) & 1;
      int pcn = (c > 0) ? pcnt[pb] : 0;
      if (pcn > 0) {
        int w = t & 127;
        int h = t >> 7;                 // even/odd split of kept rows
        u64 acc = 0;
        for (int i0 = h; i0 < pcn; i0 += 16) {
          int i1 = i0 + 2,  i2 = i0 + 4,  i3 = i0 + 6;
          int i4 = i0 + 8,  i5 = i0 + 10, i6 = i0 + 12, i7 = i0 + 14;
          int lim = pcn - 1;
          int r0 = plist[pb][i0];
          int r1 = plist[pb][i1 < pcn ? i1 : lim];
          int r2 = plist[pb][i2 < pcn ? i2 : lim];
          int r3 = plist[pb][i3 < pcn ? i3 : lim];
          int r4 = plist[pb][i4 < pcn ? i4 : lim];
          int r5 = plist[pb][i5 < pcn ? i5 : lim];
          int r6 = plist[pb][i6 < pcn ? i6 : lim];
          int r7 = plist[pb][i7 < pcn ? i7 : lim];
          u64 v0 = M[(size_t)r0 * nw + w];
          u64 v1 = M[(size_t)r1 * nw + w];
          u64 v2 = M[(size_t)r2 * nw + w];
          u64 v3 = M[(size_t)r3 * nw + w];
          u64 v4 = M[(size_t)r4 * nw + w];
          u64 v5 = M[(size_t)r5 * nw + w];
          u64 v6 = M[(size_t)r6 * nw + w];
          u64 v7 = M[(size_t)r7 * nw + w];
          acc |= v0;
          acc |= (i1 < pcn) ? v1 : 0ULL;
          acc |= (i2 < pcn) ? v2 : 0ULL;
          acc |= (i3 < pcn) ? v3 : 0ULL;
          acc |= (i4 < pcn) ? v4 : 0ULL;
          acc |= (i5 < pcn) ? v5 : 0ULL;
          acc |= (i6 < pcn) ? v6 : 0ULL;
          acc |= (i7 < pcn) ? v7 : 0ULL;
        }
        if (acc) atomicAnd(&live[w], ~acc);
      }
    }
    __syncthreads();

    // ---- phase B: wave 0 scans chunk c; waves 2-3 prefetch diag(c+1) ----
    if (wave == 0) {
      int lane = t;  // wave 0: t == lane
      u64 rem[CW];
#pragma unroll
      for (int q = 0; q < CW; ++q) {
        int w = c * CW + q;
        rem[q] = (w < nw) ? live[w] : 0ULL;
      }
      int kc = 0;
      bool stop = false;
#pragma unroll
      for (int q = 0; q < CW; ++q) {
        if (stop) break;
        while (rem[q]) {
          int b = __builtin_ctzll(rem[q]);
          int pl_ = q * 64 + b;
          int p = c * CH + pl_;
          if (lane == 0) {
            plist[cbuf][kc] = p;
            if (out < maxp) sel[out] = p;
          }
          ++kc; ++out;
          if (out >= maxp) { stop = true; break; }
          u64 s0 = dbuf[cbuf][pl_][0];
          u64 s1 = dbuf[cbuf][pl_][1];
          u64 s2 = dbuf[cbuf][pl_][2];
          u64 s3 = dbuf[cbuf][pl_][3];
          rem[0] &= ~s0; rem[1] &= ~s1; rem[2] &= ~s2; rem[3] &= ~s3;
          u64 mle = (b == 63) ? ~0ULL : ((1ULL << (b + 1)) - 1ULL);
          rem[q] &= ~mle;
        }
      }
      if (lane == 0) {
        pcnt[cbuf] = kc;
        if (stop) done_s = 1;
      }
    } else if (wave >= 2) {
      int c1 = c + 1;
      if (c1 < nch) {
        int j = t - 128;  // 0..127 -> rows j, j+128 of next chunk
#pragma unroll
        for (int rr = 0; rr < 2; ++rr) {
          int rl = j + rr * 128;
          int r = c1 * CH + rl;
#pragma unroll
          for (int q = 0; q < CW; ++q) {
            int w = c1 * CW + q;
            dbuf[c1 & 1][rl][q] =
                (r < n && w < nw) ? M[(size_t)r * nw + w] : 0ULL;
          }
        }
      }
    }
    __syncthreads();
    if (done_s) break;
  }
  if (t == 0) *cnt = (out < maxp) ? out : maxp;
}

// ---------------- K4: gather outputs ----------------
__global__ void k_emit(const float* __restrict__ preds,
                       const int* __restrict__ sidx,
                       const int* __restrict__ sel,
                       const int* __restrict__ cnt,
                       int maxp, float* __restrict__ out) {
  int k = blockIdx.x * blockDim.x + threadIdx.x;
  if (k >= maxp) return;
  int nk = *cnt;
  if (k < nk) {
    int p = sel[k];
    int orig = sidx[p];
#pragma unroll
    for (int q = 0; q < 5; ++q) out[k * 5 + q] = preds[orig * 5 + q];
    out[(size_t)maxp * 5 + k] = (float)orig;
  } else {
#pragma unroll
    for (int q = 0; q < 5; ++q) out[k * 5 + q] = 0.0f;
    out[(size_t)maxp * 5 + k] = -1.0f;
  }
}

extern "C" void kernel_launch(void* const* d_in, const int* in_sizes, int n_in,
                              void* d_out, int out_size, void* d_ws, size_t ws_size,
                              hipStream_t stream) {
  const float* preds = (const float*)d_in[0];
  const float* thr   = (const float*)d_in[1];
  float* out = (float*)d_out;
  int n    = in_sizes[0] / 5;          // 8192
  int maxp = out_size / 6;             // 1000
  int nw   = (n + 63) / 64;            // 128

  char* ws = (char*)d_ws;
  u64* M = (u64*)ws;
  size_t off = (size_t)n * nw * sizeof(u64);                 // 8 MB
  float* sboxes = (float*)(ws + off);  off += (size_t)n * 4 * sizeof(float);
  int*   sidx   = (int*)(ws + off);    off += (size_t)n * sizeof(int);
  int*   sel    = (int*)(ws + off);    off += (size_t)maxp * sizeof(int);
  int*   cnt    = (int*)(ws + off);

  hipLaunchKernelGGL(k_rank, dim3((n + 255) / 256), dim3(256), 0, stream,
                     preds, n, sboxes, sidx);
  hipLaunchKernelGGL(k_mask, dim3(nw, nw), dim3(64), 0, stream,
                     sboxes, n, thr, M, nw);
  hipLaunchKernelGGL(k_scan, dim3(1), dim3(256), 0, stream,
                     M, n, nw, maxp, sel, cnt);
  hipLaunchKernelGGL(k_emit, dim3((maxp + 255) / 256), dim3(256), 0, stream,
                     preds, sidx, sel, cnt, maxp, out);
}

// Round 6
// 300.925 us; speedup vs baseline: 1.7290x; 1.5681x over previous
//
#include <hip/hip_runtime.h>

typedef unsigned long long u64;

#define CH 256   // cols (boxes) per scan chunk
#define CW 4     // 64-bit words per chunk

// ---------------- K1a: partial rank counts (no atomics) ----------------
// pc[y*n + i] = #{j in column-chunk y: conf_j > conf_i || (== && j < i)}
__global__ __launch_bounds__(256)
void k_rank_part(const float* __restrict__ preds, int n, int cpb,
                 int* __restrict__ pc) {
  __shared__ float cs[1024];
  int c0 = blockIdx.y * cpb;
  int cn = min(cpb, n - c0);
  for (int j = threadIdx.x; j < cn; j += blockDim.x)
    cs[j] = preds[(c0 + j) * 5 + 4];
  __syncthreads();
  int i = blockIdx.x * blockDim.x + threadIdx.x;
  if (i >= n) return;
  float ci = preds[i * 5 + 4];
  int cnt = 0;
  const float4* cs4 = (const float4*)cs;
  int cn4 = cn >> 2;
  for (int j4 = 0; j4 < cn4; ++j4) {
    float4 c4 = cs4[j4];
    int jb = c0 + j4 * 4;
    cnt += (c4.x > ci) || (c4.x == ci && (jb + 0) < i);
    cnt += (c4.y > ci) || (c4.y == ci && (jb + 1) < i);
    cnt += (c4.z > ci) || (c4.z == ci && (jb + 2) < i);
    cnt += (c4.w > ci) || (c4.w == ci && (jb + 3) < i);
  }
  for (int j = cn4 * 4; j < cn; ++j)
    cnt += (cs[j] > ci) || (cs[j] == ci && (c0 + j) < i);
  pc[(size_t)blockIdx.y * n + i] = cnt;
}

// ---------------- K1b: sum partials + scatter ----------------
__global__ __launch_bounds__(256)
void k_scatter(const float* __restrict__ preds, const int* __restrict__ pc,
               int n, int nyb, float* __restrict__ sboxes,
               int* __restrict__ sidx) {
  int i = blockIdx.x * blockDim.x + threadIdx.x;
  if (i >= n) return;
  int pos = 0;
  for (int y = 0; y < nyb; ++y) pos += pc[(size_t)y * n + i];
  sboxes[pos * 4 + 0] = preds[i * 5 + 0];
  sboxes[pos * 4 + 1] = preds[i * 5 + 1];
  sboxes[pos * 4 + 2] = preds[i * 5 + 2];
  sboxes[pos * 4 + 3] = preds[i * 5 + 3];
  sidx[pos] = i;
}

// ---------------- K2: suppression bitmask, row-major ----------------
// M[row*nw + w] : bit j = IoU(row, col=w*64+j) > thresh && col > row
// Only w >= row/64 is written; sub-diagonal words are never consulted.
__global__ void k_mask(const float* __restrict__ sboxes, int n,
                       const float* __restrict__ thr_p,
                       u64* __restrict__ M, int nw) {
  int wx = blockIdx.x;  // column word
  int ry = blockIdx.y;  // row group
  if (wx < ry) return;
  int lane = threadIdx.x;

  __shared__ float4 cb[64];
  __shared__ float cbar[64];
  const float4* sb4 = (const float4*)sboxes;
  int col0 = wx * 64;
  int cj = col0 + lane;
  int cjc = cj < n ? cj : n - 1;
  {
    float4 b4 = sb4[cjc];
    cb[lane] = b4;
    cbar[lane] = __fmul_rn(__fsub_rn(b4.z, b4.x), __fsub_rn(b4.w, b4.y));
  }
  __syncthreads();

  int row = ry * 64 + lane;
  if (row >= n) return;
  float th = *thr_p;
  float4 r4 = sb4[row];
  float rarea = __fmul_rn(__fsub_rn(r4.z, r4.x), __fsub_rn(r4.w, r4.y));

  u64 w = 0;
#pragma unroll 8
  for (int j = 0; j < 64; ++j) {
    float4 c4 = cb[j];
    float ix1 = fmaxf(r4.x, c4.x);
    float iy1 = fmaxf(r4.y, c4.y);
    float ix2 = fminf(r4.z, c4.z);
    float iy2 = fminf(r4.w, c4.w);
    float iw = fmaxf(__fsub_rn(ix2, ix1), 0.0f);
    float ih = fmaxf(__fsub_rn(iy2, iy1), 0.0f);
    float inter = __fmul_rn(iw, ih);
    float denom = __fadd_rn(__fsub_rn(__fadd_rn(rarea, cbar[j]), inter), 1e-12f);
    float iou = __fdiv_rn(inter, denom);
    int col = col0 + j;
    bool sup = (col > row) && (col < n) && (iou > th);
    w |= ((u64)sup) << j;
  }
  M[(size_t)row * nw + wx] = w;
}

// wave-uniform 64-bit broadcast from lane b via v_readlane (VALU, no LDS pipe)
__device__ __forceinline__ u64 bcast64(u64 v, int b) {
  unsigned lo = __builtin_amdgcn_readlane((unsigned)v, b);
  unsigned hi = __builtin_amdgcn_readlane((unsigned)(v >> 32), b);
  return ((u64)hi << 32) | lo;
}

// ---------------- K3: incremental chunked greedy scan (1 WG, 4 waves) ----------------
// live[w]: running keep-mask. Per chunk:
//   A) all 256 threads AND prev chunk's kept rows out of live[] (batched
//      coalesced loads, LDS atomicAnd).
//   B) wave 0: diag tile LDS->registers (lane l owns rows l,64+l,128+l,192+l),
//      then serial greedy bit-scan with readlane broadcasts (pure VALU chain);
//      waves 2-3 prefetch chunk c+1's diag tile into the other LDS buffer.
__global__ __launch_bounds__(256, 1)
void k_scan(const u64* __restrict__ M, int n, int nw, int maxp,
            int* __restrict__ sel, int* __restrict__ cnt) {
  __shared__ u64 live[128];
  __shared__ u64 dbuf[2][CH][CW];
  __shared__ int plist[2][CH];
  __shared__ int pcnt[2];
  __shared__ int done_s;
  int t = threadIdx.x;           // 0..255
  int wave = t >> 6;
  int lane = t & 63;
  int nch = (nw + CW - 1) / CW;

  if (t < 128) {
    u64 v = ~0ULL;
    int base = t * 64;
    if (t >= nw || base >= n) v = 0ULL;
    else if (base + 64 > n) v = (1ULL << (n - base)) - 1ULL;
    live[t] = v;
  }
  if (t == 0) { pcnt[0] = 0; pcnt[1] = 0; done_s = 0; }
  // prologue: load diag tile of chunk 0 (rows 0..255 x words 0..3)
  {
    const u64* src = M + (size_t)t * nw;
#pragma unroll
    for (int q = 0; q < CW; ++q)
      dbuf[0][t][q] = (t < n && q < nw) ? src[q] : 0ULL;
  }
  __syncthreads();

  int out = 0;

  for (int c = 0; c < nch; ++c) {
    int cbuf = c & 1;

    // ---- phase A: apply previous chunk's kept rows to live[] ----
    {
      int pb = (c - 1) & 1;
      int pcn = (c > 0) ? pcnt[pb] : 0;
      if (pcn > 0) {
        int w = t & 127;
        int h = t >> 7;                 // even/odd split of kept rows
        u64 acc = 0;
        for (int i0 = h; i0 < pcn; i0 += 16) {
          int i1 = i0 + 2,  i2 = i0 + 4,  i3 = i0 + 6;
          int i4 = i0 + 8,  i5 = i0 + 10, i6 = i0 + 12, i7 = i0 + 14;
          int lim = pcn - 1;
          int r0 = plist[pb][i0];
          int r1 = plist[pb][i1 < pcn ? i1 : lim];
          int r2 = plist[pb][i2 < pcn ? i2 : lim];
          int r3 = plist[pb][i3 < pcn ? i3 : lim];
          int r4 = plist[pb][i4 < pcn ? i4 : lim];
          int r5 = plist[pb][i5 < pcn ? i5 : lim];
          int r6 = plist[pb][i6 < pcn ? i6 : lim];
          int r7 = plist[pb][i7 < pcn ? i7 : lim];
          u64 v0 = M[(size_t)r0 * nw + w];
          u64 v1 = M[(size_t)r1 * nw + w];
          u64 v2 = M[(size_t)r2 * nw + w];
          u64 v3 = M[(size_t)r3 * nw + w];
          u64 v4 = M[(size_t)r4 * nw + w];
          u64 v5 = M[(size_t)r5 * nw + w];
          u64 v6 = M[(size_t)r6 * nw + w];
          u64 v7 = M[(size_t)r7 * nw + w];
          acc |= v0;
          acc |= (i1 < pcn) ? v1 : 0ULL;
          acc |= (i2 < pcn) ? v2 : 0ULL;
          acc |= (i3 < pcn) ? v3 : 0ULL;
          acc |= (i4 < pcn) ? v4 : 0ULL;
          acc |= (i5 < pcn) ? v5 : 0ULL;
          acc |= (i6 < pcn) ? v6 : 0ULL;
          acc |= (i7 < pcn) ? v7 : 0ULL;
        }
        if (acc) atomicAnd(&live[w], ~acc);
      }
    }
    __syncthreads();

    // ---- phase B: wave 0 scans chunk c; waves 2-3 prefetch diag(c+1) ----
    if (wave == 0) {
      // diag tile -> registers: lane owns rows lane, 64+lane, 128+lane, 192+lane
      u64 d[CW][CW];
#pragma unroll
      for (int q = 0; q < CW; ++q)
#pragma unroll
        for (int w = 0; w < CW; ++w)
          d[q][w] = dbuf[cbuf][q * 64 + lane][w];

      u64 rem[CW];
#pragma unroll
      for (int q = 0; q < CW; ++q) {
        int w = c * CW + q;
        rem[q] = (w < nw) ? live[w] : 0ULL;
      }
      int kc = 0;
      bool stop = false;
#pragma unroll
      for (int q = 0; q < CW; ++q) {
        if (stop) break;
        while (rem[q]) {
          int b = (int)__builtin_ctzll(rem[q]);
          int p = c * CH + q * 64 + b;
          if (lane == 0) {
            plist[cbuf][kc] = p;
            if (out < maxp) sel[out] = p;
          }
          ++kc; ++out;
          if (out >= maxp) { stop = true; break; }
          u64 s0 = bcast64(d[q][0], b);
          u64 s1 = bcast64(d[q][1], b);
          u64 s2 = bcast64(d[q][2], b);
          u64 s3 = bcast64(d[q][3], b);
          rem[q] &= rem[q] - 1;   // consume bit b (lower bits already 0)
          rem[0] &= ~s0; rem[1] &= ~s1; rem[2] &= ~s2; rem[3] &= ~s3;
        }
      }
      if (lane == 0) {
        pcnt[cbuf] = kc;
        if (stop) done_s = 1;
      }
    } else if (wave >= 2) {
      int c1 = c + 1;
      if (c1 < nch) {
        int j = t - 128;  // 0..127 -> rows j, j+128 of next chunk
#pragma unroll
        for (int rr = 0; rr < 2; ++rr) {
          int rl = j + rr * 128;
          int r = c1 * CH + rl;
#pragma unroll
          for (int q = 0; q < CW; ++q) {
            int w = c1 * CW + q;
            dbuf[c1 & 1][rl][q] =
                (r < n && w < nw) ? M[(size_t)r * nw + w] : 0ULL;
          }
        }
      }
    }
    __syncthreads();
    if (done_s) break;
  }
  if (t == 0) *cnt = (out < maxp) ? out : maxp;
}

// ---------------- K4: gather outputs ----------------
__global__ void k_emit(const float* __restrict__ preds,
                       const int* __restrict__ sidx,
                       const int* __restrict__ sel,
                       const int* __restrict__ cnt,
                       int maxp, float* __restrict__ out) {
  int k = blockIdx.x * blockDim.x + threadIdx.x;
  if (k >= maxp) return;
  int nk = *cnt;
  if (k < nk) {
    int p = sel[k];
    int orig = sidx[p];
#pragma unroll
    for (int q = 0; q < 5; ++q) out[k * 5 + q] = preds[orig * 5 + q];
    out[(size_t)maxp * 5 + k] = (float)orig;
  } else {
#pragma unroll
    for (int q = 0; q < 5; ++q) out[k * 5 + q] = 0.0f;
    out[(size_t)maxp * 5 + k] = -1.0f;
  }
}

extern "C" void kernel_launch(void* const* d_in, const int* in_sizes, int n_in,
                              void* d_out, int out_size, void* d_ws, size_t ws_size,
                              hipStream_t stream) {
  const float* preds = (const float*)d_in[0];
  const float* thr   = (const float*)d_in[1];
  float* out = (float*)d_out;
  int n    = in_sizes[0] / 5;          // 8192
  int maxp = out_size / 6;             // 1000
  int nw   = (n + 63) / 64;            // 128
  int cpb  = 1024;
  int nyb  = (n + cpb - 1) / cpb;      // 8

  char* ws = (char*)d_ws;
  u64* M = (u64*)ws;
  size_t off = (size_t)n * nw * sizeof(u64);                 // 8 MB
  float* sboxes = (float*)(ws + off);  off += (size_t)n * 4 * sizeof(float);
  int*   sidx   = (int*)(ws + off);    off += (size_t)n * sizeof(int);
  int*   sel    = (int*)(ws + off);    off += (size_t)maxp * sizeof(int);
  int*   cnt    = (int*)(ws + off);    off += sizeof(int) * 4;
  int*   pc     = (int*)(ws + off);    // nyb * n ints (256 KB)

  hipLaunchKernelGGL(k_rank_part, dim3((n + 255) / 256, nyb), dim3(256), 0,
                     stream, preds, n, cpb, pc);
  hipLaunchKernelGGL(k_scatter, dim3((n + 255) / 256), dim3(256), 0, stream,
                     preds, pc, n, nyb, sboxes, sidx);
  hipLaunchKernelGGL(k_mask, dim3(nw, nw), dim3(64), 0, stream,
                     sboxes, n, thr, M, nw);
  hipLaunchKernelGGL(k_scan, dim3(1), dim3(256), 0, stream,
                     M, n, nw, maxp, sel, cnt);
  hipLaunchKernelGGL(k_emit, dim3((maxp + 255) / 256), dim3(256), 0, stream,
                     preds, sidx, sel, cnt, maxp, out);
}

// Round 8
// 229.829 us; speedup vs baseline: 2.2639x; 1.3093x over previous
//
#include <hip/hip_runtime.h>

typedef unsigned long long u64;

#define CH 256   // cols (boxes) per scan chunk
#define CW 4     // 64-bit words per chunk

// ---------------- K1a: partial rank counts (no atomics) ----------------
__global__ __launch_bounds__(256)
void k_rank_part(const float* __restrict__ preds, int n, int cpb,
                 int* __restrict__ pc) {
  __shared__ float cs[1024];
  int c0 = blockIdx.y * cpb;
  int cn = min(cpb, n - c0);
  for (int j = threadIdx.x; j < cn; j += blockDim.x)
    cs[j] = preds[(c0 + j) * 5 + 4];
  __syncthreads();
  int i = blockIdx.x * blockDim.x + threadIdx.x;
  if (i >= n) return;
  float ci = preds[i * 5 + 4];
  int cnt = 0;
  const float4* cs4 = (const float4*)cs;
  int cn4 = cn >> 2;
  for (int j4 = 0; j4 < cn4; ++j4) {
    float4 c4 = cs4[j4];
    int jb = c0 + j4 * 4;
    cnt += (c4.x > ci) || (c4.x == ci && (jb + 0) < i);
    cnt += (c4.y > ci) || (c4.y == ci && (jb + 1) < i);
    cnt += (c4.z > ci) || (c4.z == ci && (jb + 2) < i);
    cnt += (c4.w > ci) || (c4.w == ci && (jb + 3) < i);
  }
  for (int j = cn4 * 4; j < cn; ++j)
    cnt += (cs[j] > ci) || (cs[j] == ci && (c0 + j) < i);
  pc[(size_t)blockIdx.y * n + i] = cnt;
}

// ---------------- K1b: sum partials + scatter ----------------
__global__ __launch_bounds__(256)
void k_scatter(const float* __restrict__ preds, const int* __restrict__ pc,
               int n, int nyb, float* __restrict__ sboxes,
               int* __restrict__ sidx) {
  int i = blockIdx.x * blockDim.x + threadIdx.x;
  if (i >= n) return;
  int pos = 0;
  for (int y = 0; y < nyb; ++y) pos += pc[(size_t)y * n + i];
  sboxes[pos * 4 + 0] = preds[i * 5 + 0];
  sboxes[pos * 4 + 1] = preds[i * 5 + 1];
  sboxes[pos * 4 + 2] = preds[i * 5 + 2];
  sboxes[pos * 4 + 3] = preds[i * 5 + 3];
  sidx[pos] = i;
}

// ---------------- K2: suppression bitmask, row-major ----------------
// M[row*nw + w] : bit j = IoU(row, col=w*64+j) > thresh && col > row
// Only w >= row/64 is valid; sub-diagonal words are garbage but only ever
// AND into already-consumed scan words (provably harmless).
__global__ void k_mask(const float* __restrict__ sboxes, int n,
                       const float* __restrict__ thr_p,
                       u64* __restrict__ M, int nw) {
  int wx = blockIdx.x;  // column word
  int ry = blockIdx.y;  // row group
  if (wx < ry) return;
  int lane = threadIdx.x;

  __shared__ float4 cb[64];
  __shared__ float cbar[64];
  const float4* sb4 = (const float4*)sboxes;
  int col0 = wx * 64;
  int cj = col0 + lane;
  int cjc = cj < n ? cj : n - 1;
  {
    float4 b4 = sb4[cjc];
    cb[lane] = b4;
    cbar[lane] = __fmul_rn(__fsub_rn(b4.z, b4.x), __fsub_rn(b4.w, b4.y));
  }
  __syncthreads();

  int row = ry * 64 + lane;
  if (row >= n) return;
  float th = *thr_p;
  float4 r4 = sb4[row];
  float rarea = __fmul_rn(__fsub_rn(r4.z, r4.x), __fsub_rn(r4.w, r4.y));

  u64 w = 0;
#pragma unroll 8
  for (int j = 0; j < 64; ++j) {
    float4 c4 = cb[j];
    float ix1 = fmaxf(r4.x, c4.x);
    float iy1 = fmaxf(r4.y, c4.y);
    float ix2 = fminf(r4.z, c4.z);
    float iy2 = fminf(r4.w, c4.w);
    float iw = fmaxf(__fsub_rn(ix2, ix1), 0.0f);
    float ih = fmaxf(__fsub_rn(iy2, iy1), 0.0f);
    float inter = __fmul_rn(iw, ih);
    float denom = __fadd_rn(__fsub_rn(__fadd_rn(rarea, cbar[j]), inter), 1e-12f);
    float iou = __fdiv_rn(inter, denom);
    int col = col0 + j;
    bool sup = (col > row) && (col < n) && (iou > th);
    w |= ((u64)sup) << j;
  }
  M[(size_t)row * nw + wx] = w;
}

// wave-uniform 64-bit broadcast from lane bs (SGPR) via v_readlane — pure VALU
__device__ __forceinline__ u64 bcast64(u64 v, int bs) {
  unsigned lo = __builtin_amdgcn_readlane((unsigned)v, bs);
  unsigned hi = __builtin_amdgcn_readlane((unsigned)(v >> 32), bs);
  return ((u64)hi << 32) | lo;
}

// serial greedy scan of one 64-box word; NO memory ops on the chain.
// Kept boxes recorded as a uniform bitmask (off the dependence chain);
// positions reconstructed afterwards by popcount ranking.
#define SCAN_WORD(Q, DQ0, DQ1, DQ2, DQ3)                                   \
  if (!stop)                                                               \
    while (rem##Q) {                                                       \
      int b = (int)__builtin_ctzll(rem##Q);                                \
      int bs = __builtin_amdgcn_readfirstlane(b);                          \
      kept##Q |= (u64)1 << bs;                                             \
      ++kc; ++out;                                                         \
      if (out >= maxp) { stop = true; break; }                             \
      u64 s0 = bcast64(DQ0, bs), s1 = bcast64(DQ1, bs),                    \
          s2 = bcast64(DQ2, bs), s3 = bcast64(DQ3, bs);                    \
      rem##Q &= rem##Q - 1;                                                \
      rem0 &= ~s0; rem1 &= ~s1; rem2 &= ~s2; rem3 &= ~s3;                  \
    }

// dump kept positions of word Q: lane handles bit 'lane'
#define DUMP_WORD(Q, BASE)                                                 \
  if (kept##Q & lbit) {                                                    \
    int r = (BASE) + (int)__popcll(kept##Q & lmask);                       \
    int p = c * CH + (Q) * 64 + lane;                                      \
    plist[cbuf][r] = p;                                                    \
    int o = out0 + r;                                                      \
    if (o < maxp) sel[o] = p;                                              \
  }

// ---------------- K3: incremental chunked greedy scan (1 WG, 8 waves) ----------------
__global__ __launch_bounds__(512, 1)
void k_scan(const u64* __restrict__ M, int n, int nw, int maxp,
            int* __restrict__ sel, int* __restrict__ cnt) {
  __shared__ u64 live[128];
  __shared__ u64 dbuf[2][CH][CW];
  __shared__ int plist[2][CH];
  __shared__ int pcnt[2];
  __shared__ int done_s;
  int t = threadIdx.x;           // 0..511
  int wave = t >> 6;
  int lane = t & 63;
  int nch = (nw + CW - 1) / CW;

  if (t < 128) {
    u64 v = ~0ULL;
    int base = t * 64;
    if (t >= nw || base >= n) v = 0ULL;
    else if (base + 64 > n) v = (1ULL << (n - base)) - 1ULL;
    live[t] = v;
  }
  if (t == 0) { pcnt[0] = 0; pcnt[1] = 0; done_s = 0; }
  if (t < CH) {   // prologue: diag tile of chunk 0
    const u64* src = M + (size_t)t * nw;
#pragma unroll
    for (int q = 0; q < CW; ++q)
      dbuf[0][t][q] = (t < n && q < nw) ? src[q] : 0ULL;
  }
  __syncthreads();

  int out = 0;

  for (int c = 0; c < nch; ++c) {
    int cbuf = c & 1;

    // ---- phase A: apply previous chunk's kept rows to live[] (4 thr/word) ----
    {
      int pb = (c - 1) & 1;
      int pcn = (c > 0) ? pcnt[pb] : 0;
      int w = t & 127;
      int h = t >> 7;                 // 0..3
      if (pcn > 0 && w < nw) {
        u64 acc = 0;
        for (int i0 = h; i0 < pcn; i0 += 32) {
          int lim = pcn - 1;
          int j1 = i0 + 4,  j2 = i0 + 8,  j3 = i0 + 12;
          int j4 = i0 + 16, j5 = i0 + 20, j6 = i0 + 24, j7 = i0 + 28;
          int r0 = plist[pb][i0];
          int r1 = plist[pb][j1 < pcn ? j1 : lim];
          int r2 = plist[pb][j2 < pcn ? j2 : lim];
          int r3 = plist[pb][j3 < pcn ? j3 : lim];
          int r4 = plist[pb][j4 < pcn ? j4 : lim];
          int r5 = plist[pb][j5 < pcn ? j5 : lim];
          int r6 = plist[pb][j6 < pcn ? j6 : lim];
          int r7 = plist[pb][j7 < pcn ? j7 : lim];
          u64 v0 = M[(size_t)r0 * nw + w];
          u64 v1 = M[(size_t)r1 * nw + w];
          u64 v2 = M[(size_t)r2 * nw + w];
          u64 v3 = M[(size_t)r3 * nw + w];
          u64 v4 = M[(size_t)r4 * nw + w];
          u64 v5 = M[(size_t)r5 * nw + w];
          u64 v6 = M[(size_t)r6 * nw + w];
          u64 v7 = M[(size_t)r7 * nw + w];
          acc |= v0;
          acc |= (j1 < pcn) ? v1 : 0ULL;
          acc |= (j2 < pcn) ? v2 : 0ULL;
          acc |= (j3 < pcn) ? v3 : 0ULL;
          acc |= (j4 < pcn) ? v4 : 0ULL;
          acc |= (j5 < pcn) ? v5 : 0ULL;
          acc |= (j6 < pcn) ? v6 : 0ULL;
          acc |= (j7 < pcn) ? v7 : 0ULL;
        }
        if (acc) atomicAnd(&live[w], ~acc);
      }
    }
    __syncthreads();

    // ---- phase B: wave 0 scans chunk c; waves 4-7 prefetch diag(c+1) ----
    if (wave == 0) {
      // diag tile -> 16 NAMED u64 registers (lane owns rows lane,64+,128+,192+)
      u64 d00 = dbuf[cbuf][lane][0],       d01 = dbuf[cbuf][lane][1],
          d02 = dbuf[cbuf][lane][2],       d03 = dbuf[cbuf][lane][3];
      u64 d10 = dbuf[cbuf][64 + lane][0],  d11 = dbuf[cbuf][64 + lane][1],
          d12 = dbuf[cbuf][64 + lane][2],  d13 = dbuf[cbuf][64 + lane][3];
      u64 d20 = dbuf[cbuf][128 + lane][0], d21 = dbuf[cbuf][128 + lane][1],
          d22 = dbuf[cbuf][128 + lane][2], d23 = dbuf[cbuf][128 + lane][3];
      u64 d30 = dbuf[cbuf][192 + lane][0], d31 = dbuf[cbuf][192 + lane][1],
          d32 = dbuf[cbuf][192 + lane][2], d33 = dbuf[cbuf][192 + lane][3];

      u64 rem0 = (c * CW + 0 < nw) ? live[c * CW + 0] : 0ULL;
      u64 rem1 = (c * CW + 1 < nw) ? live[c * CW + 1] : 0ULL;
      u64 rem2 = (c * CW + 2 < nw) ? live[c * CW + 2] : 0ULL;
      u64 rem3 = (c * CW + 3 < nw) ? live[c * CW + 3] : 0ULL;

      u64 kept0 = 0, kept1 = 0, kept2 = 0, kept3 = 0;
      int kc = 0;
      int out0 = out;
      bool stop = false;

      SCAN_WORD(0, d00, d01, d02, d03)
      SCAN_WORD(1, d10, d11, d12, d13)
      SCAN_WORD(2, d20, d21, d22, d23)
      SCAN_WORD(3, d30, d31, d32, d33)

      // reconstruct kept positions via popcount ranking (greedy order preserved)
      {
        int b1 = (int)__popcll(kept0);
        int b2 = b1 + (int)__popcll(kept1);
        int b3 = b2 + (int)__popcll(kept2);
        u64 lbit = (u64)1 << lane;
        u64 lmask = lbit - 1;
        DUMP_WORD(0, 0)
        DUMP_WORD(1, b1)
        DUMP_WORD(2, b2)
        DUMP_WORD(3, b3)
      }
      if (lane == 0) {
        pcnt[cbuf] = kc;
        if (stop) done_s = 1;
      }
    } else if (wave >= 4) {
      int c1 = c + 1;
      if (c1 < nch) {
        int rl = t - 256;   // 0..255 -> one row each
        int r = c1 * CH + rl;
#pragma unroll
        for (int q = 0; q < CW; ++q) {
          int w = c1 * CW + q;
          dbuf[c1 & 1][rl][q] =
              (r < n && w < nw) ? M[(size_t)r * nw + w] : 0ULL;
        }
      }
    }
    __syncthreads();
    if (done_s) break;
  }
  if (t == 0) *cnt = (out < maxp) ? out : maxp;
}

// ---------------- K4: gather outputs ----------------
__global__ void k_emit(const float* __restrict__ preds,
                       const int* __restrict__ sidx,
                       const int* __restrict__ sel,
                       const int* __restrict__ cnt,
                       int maxp, float* __restrict__ out) {
  int k = blockIdx.x * blockDim.x + threadIdx.x;
  if (k >= maxp) return;
  int nk = *cnt;
  if (k < nk) {
    int p = sel[k];
    int orig = sidx[p];
#pragma unroll
    for (int q = 0; q < 5; ++q) out[k * 5 + q] = preds[orig * 5 + q];
    out[(size_t)maxp * 5 + k] = (float)orig;
  } else {
#pragma unroll
    for (int q = 0; q < 5; ++q) out[k * 5 + q] = 0.0f;
    out[(size_t)maxp * 5 + k] = -1.0f;
  }
}

extern "C" void kernel_launch(void* const* d_in, const int* in_sizes, int n_in,
                              void* d_out, int out_size, void* d_ws, size_t ws_size,
                              hipStream_t stream) {
  const float* preds = (const float*)d_in[0];
  const float* thr   = (const float*)d_in[1];
  float* out = (float*)d_out;
  int n    = in_sizes[0] / 5;          // 8192
  int maxp = out_size / 6;             // 1000
  int nw   = (n + 63) / 64;            // 128
  int cpb  = 1024;
  int nyb  = (n + cpb - 1) / cpb;      // 8

  char* ws = (char*)d_ws;
  u64* M = (u64*)ws;
  size_t off = (size_t)n * nw * sizeof(u64);                 // 8 MB
  float* sboxes = (float*)(ws + off);  off += (size_t)n * 4 * sizeof(float);
  int*   sidx   = (int*)(ws + off);    off += (size_t)n * sizeof(int);
  int*   sel    = (int*)(ws + off);    off += (size_t)maxp * sizeof(int);
  int*   cnt    = (int*)(ws + off);    off += sizeof(int) * 4;
  int*   pc     = (int*)(ws + off);    // nyb * n ints

  hipLaunchKernelGGL(k_rank_part, dim3((n + 255) / 256, nyb), dim3(256), 0,
                     stream, preds, n, cpb, pc);
  hipLaunchKernelGGL(k_scatter, dim3((n + 255) / 256), dim3(256), 0, stream,
                     preds, pc, n, nyb, sboxes, sidx);
  hipLaunchKernelGGL(k_mask, dim3(nw, nw), dim3(64), 0, stream,
                     sboxes, n, thr, M, nw);
  hipLaunchKernelGGL(k_scan, dim3(1), dim3(512), 0, stream,
                     M, n, nw, maxp, sel, cnt);
  hipLaunchKernelGGL(k_emit, dim3((maxp + 255) / 256), dim3(256), 0, stream,
                     preds, sidx, sel, cnt, maxp, out);
}

// Round 9
// 225.167 us; speedup vs baseline: 2.3108x; 1.0207x over previous
//
#include <hip/hip_runtime.h>

typedef unsigned long long u64;

#define CH 256   // cols (boxes) per scan chunk
#define CW 4     // 64-bit words per chunk

// ---------------- K1a: partial rank counts (no atomics) ----------------
__global__ __launch_bounds__(256)
void k_rank_part(const float* __restrict__ preds, int n, int cpb,
                 int* __restrict__ pc) {
  __shared__ float cs[1024];
  int c0 = blockIdx.y * cpb;
  int cn = min(cpb, n - c0);
  for (int j = threadIdx.x; j < cn; j += blockDim.x)
    cs[j] = preds[(c0 + j) * 5 + 4];
  __syncthreads();
  int i = blockIdx.x * blockDim.x + threadIdx.x;
  if (i >= n) return;
  float ci = preds[i * 5 + 4];
  int cnt = 0;
  const float4* cs4 = (const float4*)cs;
  int cn4 = cn >> 2;
  for (int j4 = 0; j4 < cn4; ++j4) {
    float4 c4 = cs4[j4];
    int jb = c0 + j4 * 4;
    cnt += (c4.x > ci) || (c4.x == ci && (jb + 0) < i);
    cnt += (c4.y > ci) || (c4.y == ci && (jb + 1) < i);
    cnt += (c4.z > ci) || (c4.z == ci && (jb + 2) < i);
    cnt += (c4.w > ci) || (c4.w == ci && (jb + 3) < i);
  }
  for (int j = cn4 * 4; j < cn; ++j)
    cnt += (cs[j] > ci) || (cs[j] == ci && (c0 + j) < i);
  pc[(size_t)blockIdx.y * n + i] = cnt;
}

// ---------------- K1b: sum partials + scatter ----------------
__global__ __launch_bounds__(256)
void k_scatter(const float* __restrict__ preds, const int* __restrict__ pc,
               int n, int nyb, float* __restrict__ sboxes,
               int* __restrict__ sidx) {
  int i = blockIdx.x * blockDim.x + threadIdx.x;
  if (i >= n) return;
  int pos = 0;
  for (int y = 0; y < nyb; ++y) pos += pc[(size_t)y * n + i];
  sboxes[pos * 4 + 0] = preds[i * 5 + 0];
  sboxes[pos * 4 + 1] = preds[i * 5 + 1];
  sboxes[pos * 4 + 2] = preds[i * 5 + 2];
  sboxes[pos * 4 + 3] = preds[i * 5 + 3];
  sidx[pos] = i;
}

// ---------------- K2: suppression bitmask, row-major ----------------
// M[row*nw + w] : bit j = IoU(row, col=w*64+j) > thresh && col > row
// Only w >= row/64 is valid; sub-diagonal words are garbage but only ever
// AND into already-consumed scan words (provably harmless).
__global__ void k_mask(const float* __restrict__ sboxes, int n,
                       const float* __restrict__ thr_p,
                       u64* __restrict__ M, int nw) {
  int wx = blockIdx.x;  // column word
  int ry = blockIdx.y;  // row group
  if (wx < ry) return;
  int lane = threadIdx.x;

  __shared__ float4 cb[64];
  __shared__ float cbar[64];
  const float4* sb4 = (const float4*)sboxes;
  int col0 = wx * 64;
  int cj = col0 + lane;
  int cjc = cj < n ? cj : n - 1;
  {
    float4 b4 = sb4[cjc];
    cb[lane] = b4;
    cbar[lane] = __fmul_rn(__fsub_rn(b4.z, b4.x), __fsub_rn(b4.w, b4.y));
  }
  __syncthreads();

  int row = ry * 64 + lane;
  if (row >= n) return;
  float th = *thr_p;
  float4 r4 = sb4[row];
  float rarea = __fmul_rn(__fsub_rn(r4.z, r4.x), __fsub_rn(r4.w, r4.y));

  u64 w = 0;
#pragma unroll 8
  for (int j = 0; j < 64; ++j) {
    float4 c4 = cb[j];
    float ix1 = fmaxf(r4.x, c4.x);
    float iy1 = fmaxf(r4.y, c4.y);
    float ix2 = fminf(r4.z, c4.z);
    float iy2 = fminf(r4.w, c4.w);
    float iw = fmaxf(__fsub_rn(ix2, ix1), 0.0f);
    float ih = fmaxf(__fsub_rn(iy2, iy1), 0.0f);
    float inter = __fmul_rn(iw, ih);
    float denom = __fadd_rn(__fsub_rn(__fadd_rn(rarea, cbar[j]), inter), 1e-12f);
    float iou = __fdiv_rn(inter, denom);
    int col = col0 + j;
    bool sup = (col > row) && (col < n) && (iou > th);
    w |= ((u64)sup) << j;
  }
  M[(size_t)row * nw + wx] = w;
}

// keep a 64-bit value resident in VGPRs (opaque def: no LDS rematerialization)
#define PIN(x) asm volatile("" : "+v"(x))

// wave-uniform 64-bit broadcast from lane bs (uniform) via v_readlane
__device__ __forceinline__ u64 bcast64(u64 v, int bs) {
  unsigned lo = __builtin_amdgcn_readlane((unsigned)v, bs);
  unsigned hi = __builtin_amdgcn_readlane((unsigned)(v >> 32), bs);
  return ((u64)hi << 32) | lo;
}

// force a wave-uniform 64-bit value into scalar registers
__device__ __forceinline__ u64 sgpr64(u64 v) {
  unsigned lo = __builtin_amdgcn_readfirstlane((unsigned)v);
  unsigned hi = __builtin_amdgcn_readfirstlane((unsigned)(v >> 32));
  return ((u64)hi << 32) | lo;
}

// serial greedy scan of one 64-box word; pure SALU/readlane chain, no memory.
#define SCAN_WORD(Q, DQ0, DQ1, DQ2, DQ3)                                   \
  if (!stop)                                                               \
    while (rem##Q) {                                                       \
      int b = (int)__builtin_ctzll(rem##Q);                                \
      kept##Q |= (u64)1 << b;                                              \
      ++out;                                                               \
      if (out >= maxp) { stop = true; break; }                             \
      u64 s0 = bcast64(DQ0, b), s1 = bcast64(DQ1, b),                      \
          s2 = bcast64(DQ2, b), s3 = bcast64(DQ3, b);                      \
      rem##Q &= rem##Q - 1;                                                \
      rem0 &= ~s0; rem1 &= ~s1; rem2 &= ~s2; rem3 &= ~s3;                  \
    }

// dump kept positions of word Q: lane handles bit 'lane'
#define DUMP_WORD(Q, BASE)                                                 \
  if (kept##Q & lbit) {                                                    \
    int r = (BASE) + (int)__popcll(kept##Q & lmask);                       \
    int p = c * CH + (Q) * 64 + lane;                                      \
    plist[cbuf][r] = p;                                                    \
    int o = out0 + r;                                                      \
    if (o < maxp) sel[o] = p;                                              \
  }

// ---------------- K3: incremental chunked greedy scan (1 WG, 8 waves) ----------------
__global__ __launch_bounds__(512, 1)
void k_scan(const u64* __restrict__ M, int n, int nw, int maxp,
            int* __restrict__ sel, int* __restrict__ cnt) {
  __shared__ u64 live[128];
  __shared__ u64 dbuf[2][CH][CW];
  __shared__ int plist[2][CH];
  __shared__ int pcnt[2];
  __shared__ int done_s;
  int t = threadIdx.x;           // 0..511
  int wave = t >> 6;
  int lane = t & 63;
  int nch = (nw + CW - 1) / CW;

  if (t < 128) {
    u64 v = ~0ULL;
    int base = t * 64;
    if (t >= nw || base >= n) v = 0ULL;
    else if (base + 64 > n) v = (1ULL << (n - base)) - 1ULL;
    live[t] = v;
  }
  if (t == 0) { pcnt[0] = 0; pcnt[1] = 0; done_s = 0; }
  if (t < CH) {   // prologue: diag tile of chunk 0
    const u64* src = M + (size_t)t * nw;
#pragma unroll
    for (int q = 0; q < CW; ++q)
      dbuf[0][t][q] = (t < n && q < nw) ? src[q] : 0ULL;
  }
  __syncthreads();

  int out = 0;

  for (int c = 0; c < nch; ++c) {
    int cbuf = c & 1;

    // ---- phase A: apply previous chunk's kept rows to live[] (4 thr/word) ----
    {
      int pb = (c - 1) & 1;
      int pcn = (c > 0) ? pcnt[pb] : 0;
      int w = t & 127;
      int h = t >> 7;                 // 0..3
      if (pcn > 0 && w < nw) {
        u64 acc = 0;
        for (int i0 = h; i0 < pcn; i0 += 32) {
          int lim = pcn - 1;
          int j1 = i0 + 4,  j2 = i0 + 8,  j3 = i0 + 12;
          int j4 = i0 + 16, j5 = i0 + 20, j6 = i0 + 24, j7 = i0 + 28;
          int r0 = plist[pb][i0];
          int r1 = plist[pb][j1 < pcn ? j1 : lim];
          int r2 = plist[pb][j2 < pcn ? j2 : lim];
          int r3 = plist[pb][j3 < pcn ? j3 : lim];
          int r4 = plist[pb][j4 < pcn ? j4 : lim];
          int r5 = plist[pb][j5 < pcn ? j5 : lim];
          int r6 = plist[pb][j6 < pcn ? j6 : lim];
          int r7 = plist[pb][j7 < pcn ? j7 : lim];
          u64 v0 = M[(size_t)r0 * nw + w];
          u64 v1 = M[(size_t)r1 * nw + w];
          u64 v2 = M[(size_t)r2 * nw + w];
          u64 v3 = M[(size_t)r3 * nw + w];
          u64 v4 = M[(size_t)r4 * nw + w];
          u64 v5 = M[(size_t)r5 * nw + w];
          u64 v6 = M[(size_t)r6 * nw + w];
          u64 v7 = M[(size_t)r7 * nw + w];
          acc |= v0;
          acc |= (j1 < pcn) ? v1 : 0ULL;
          acc |= (j2 < pcn) ? v2 : 0ULL;
          acc |= (j3 < pcn) ? v3 : 0ULL;
          acc |= (j4 < pcn) ? v4 : 0ULL;
          acc |= (j5 < pcn) ? v5 : 0ULL;
          acc |= (j6 < pcn) ? v6 : 0ULL;
          acc |= (j7 < pcn) ? v7 : 0ULL;
        }
        if (acc) atomicAnd(&live[w], ~acc);
      }
    }
    __syncthreads();

    // ---- phase B: wave 0 scans chunk c; waves 4-7 prefetch diag(c+1) ----
    if (wave == 0) {
      // diag tile -> 16 NAMED u64 registers, pinned against LDS remat
      u64 d00 = dbuf[cbuf][lane][0],       d01 = dbuf[cbuf][lane][1],
          d02 = dbuf[cbuf][lane][2],       d03 = dbuf[cbuf][lane][3];
      u64 d10 = dbuf[cbuf][64 + lane][0],  d11 = dbuf[cbuf][64 + lane][1],
          d12 = dbuf[cbuf][64 + lane][2],  d13 = dbuf[cbuf][64 + lane][3];
      u64 d20 = dbuf[cbuf][128 + lane][0], d21 = dbuf[cbuf][128 + lane][1],
          d22 = dbuf[cbuf][128 + lane][2], d23 = dbuf[cbuf][128 + lane][3];
      u64 d30 = dbuf[cbuf][192 + lane][0], d31 = dbuf[cbuf][192 + lane][1],
          d32 = dbuf[cbuf][192 + lane][2], d33 = dbuf[cbuf][192 + lane][3];
      PIN(d00); PIN(d01); PIN(d02); PIN(d03);
      PIN(d10); PIN(d11); PIN(d12); PIN(d13);
      PIN(d20); PIN(d21); PIN(d22); PIN(d23);
      PIN(d30); PIN(d31); PIN(d32); PIN(d33);

      // scan state in SGPRs: uniform rem/kept -> SALU chain
      u64 rem0 = sgpr64((c * CW + 0 < nw) ? live[c * CW + 0] : 0ULL);
      u64 rem1 = sgpr64((c * CW + 1 < nw) ? live[c * CW + 1] : 0ULL);
      u64 rem2 = sgpr64((c * CW + 2 < nw) ? live[c * CW + 2] : 0ULL);
      u64 rem3 = sgpr64((c * CW + 3 < nw) ? live[c * CW + 3] : 0ULL);

      u64 kept0 = 0, kept1 = 0, kept2 = 0, kept3 = 0;
      int out0 = out;
      bool stop = false;

      SCAN_WORD(0, d00, d01, d02, d03)
      SCAN_WORD(1, d10, d11, d12, d13)
      SCAN_WORD(2, d20, d21, d22, d23)
      SCAN_WORD(3, d30, d31, d32, d33)

      int kc = out - out0;

      // reconstruct kept positions via popcount ranking (greedy order preserved)
      {
        int b1 = (int)__popcll(kept0);
        int b2 = b1 + (int)__popcll(kept1);
        int b3 = b2 + (int)__popcll(kept2);
        u64 lbit = (u64)1 << lane;
        u64 lmask = lbit - 1;
        DUMP_WORD(0, 0)
        DUMP_WORD(1, b1)
        DUMP_WORD(2, b2)
        DUMP_WORD(3, b3)
      }
      if (lane == 0) {
        pcnt[cbuf] = kc;
        if (stop) done_s = 1;
      }
    } else if (wave >= 4) {
      int c1 = c + 1;
      if (c1 < nch) {
        int rl = t - 256;   // 0..255 -> one row each
        int r = c1 * CH + rl;
#pragma unroll
        for (int q = 0; q < CW; ++q) {
          int w = c1 * CW + q;
          dbuf[c1 & 1][rl][q] =
              (r < n && w < nw) ? M[(size_t)r * nw + w] : 0ULL;
        }
      }
    }
    __syncthreads();
    if (done_s) break;
  }
  if (t == 0) *cnt = (out < maxp) ? out : maxp;
}

// ---------------- K4: gather outputs ----------------
__global__ void k_emit(const float* __restrict__ preds,
                       const int* __restrict__ sidx,
                       const int* __restrict__ sel,
                       const int* __restrict__ cnt,
                       int maxp, float* __restrict__ out) {
  int k = blockIdx.x * blockDim.x + threadIdx.x;
  if (k >= maxp) return;
  int nk = *cnt;
  if (k < nk) {
    int p = sel[k];
    int orig = sidx[p];
#pragma unroll
    for (int q = 0; q < 5; ++q) out[k * 5 + q] = preds[orig * 5 + q];
    out[(size_t)maxp * 5 + k] = (float)orig;
  } else {
#pragma unroll
    for (int q = 0; q < 5; ++q) out[k * 5 + q] = 0.0f;
    out[(size_t)maxp * 5 + k] = -1.0f;
  }
}

extern "C" void kernel_launch(void* const* d_in, const int* in_sizes, int n_in,
                              void* d_out, int out_size, void* d_ws, size_t ws_size,
                              hipStream_t stream) {
  const float* preds = (const float*)d_in[0];
  const float* thr   = (const float*)d_in[1];
  float* out = (float*)d_out;
  int n    = in_sizes[0] / 5;          // 8192
  int maxp = out_size / 6;             // 1000
  int nw   = (n + 63) / 64;            // 128
  int cpb  = 1024;
  int nyb  = (n + cpb - 1) / cpb;      // 8

  char* ws = (char*)d_ws;
  u64* M = (u64*)ws;
  size_t off = (size_t)n * nw * sizeof(u64);                 // 8 MB
  float* sboxes = (float*)(ws + off);  off += (size_t)n * 4 * sizeof(float);
  int*   sidx   = (int*)(ws + off);    off += (size_t)n * sizeof(int);
  int*   sel    = (int*)(ws + off);    off += (size_t)maxp * sizeof(int);
  int*   cnt    = (int*)(ws + off);    off += sizeof(int) * 4;
  int*   pc     = (int*)(ws + off);    // nyb * n ints

  hipLaunchKernelGGL(k_rank_part, dim3((n + 255) / 256, nyb), dim3(256), 0,
                     stream, preds, n, cpb, pc);
  hipLaunchKernelGGL(k_scatter, dim3((n + 255) / 256), dim3(256), 0, stream,
                     preds, pc, n, nyb, sboxes, sidx);
  hipLaunchKernelGGL(k_mask, dim3(nw, nw), dim3(64), 0, stream,
                     sboxes, n, thr, M, nw);
  hipLaunchKernelGGL(k_scan, dim3(1), dim3(512), 0, stream,
                     M, n, nw, maxp, sel, cnt);
  hipLaunchKernelGGL(k_emit, dim3((maxp + 255) / 256), dim3(256), 0, stream,
                     preds, sidx, sel, cnt, maxp, out);
}